// Round 1
// baseline (227.235 us; speedup 1.0000x reference)
//
#include <hip/hip_runtime.h>

// The reference's final op is softmax over an axis of length 1:
//   hmap = hybrid[:, None, :]          # (B, 1, N)
//   out  = softmax(hmap, axis=1)       # axis length 1 -> exp(0)/exp(0) = 1.0
// `hybrid` is finite (trunc -> int32 -> float32 forces finiteness), so the
// output is exactly ones((B, 1, N), float32), independent of the input.
// The kernel therefore only needs to fill d_out with 1.0f.

__global__ void fill_ones_kernel(float* __restrict__ out, int n4, int n) {
    int i = blockIdx.x * blockDim.x + threadIdx.x;
    const float4 one4 = make_float4(1.0f, 1.0f, 1.0f, 1.0f);
    if (i < n4) {
        reinterpret_cast<float4*>(out)[i] = one4;
    }
    // Tail (n not divisible by 4) — not hit for n = 262144, kept for safety.
    int tail_start = n4 * 4;
    int t = tail_start + i;
    if (i < (n - tail_start)) {
        out[t] = 1.0f;
    }
}

extern "C" void kernel_launch(void* const* d_in, const int* in_sizes, int n_in,
                              void* d_out, int out_size, void* d_ws, size_t ws_size,
                              hipStream_t stream) {
    (void)d_in; (void)in_sizes; (void)n_in; (void)d_ws; (void)ws_size;
    float* out = reinterpret_cast<float*>(d_out);
    int n = out_size;            // 64 * 1 * 4096 = 262144
    int n4 = n / 4;              // 65536 float4 stores
    int block = 256;
    int grid = (n4 + block - 1) / block;
    if (grid < 1) grid = 1;
    fill_ones_kernel<<<grid, block, 0, stream>>>(out, n4, n);
}